// Round 1
// 171.464 us; speedup vs baseline: 1.1119x; 1.1119x over previous
//
#include <hip/hip_runtime.h>

#define T_  30
#define B_  64
#define V_  32
#define F_  128
#define L_  64
#define LF_ 64
#define TH_ 20
#define H_  4
#define HD_ 32

typedef __attribute__((ext_vector_type(8))) short bf16x8;   // 8 bf16 = 4 VGPR
typedef __attribute__((ext_vector_type(4))) float f32x4;
#define MFMA(a,b,c) __builtin_amdgcn_mfma_f32_16x16x32_bf16(a, b, c, 0, 0, 0)

__device__ __forceinline__ float bf1(unsigned short u) {
    unsigned int x = ((unsigned int)u) << 16; float f; __builtin_memcpy(&f, &x, 4); return f;
}
__device__ __forceinline__ unsigned short f2bf(float f) {
    unsigned int x; __builtin_memcpy(&x, &f, 4);
    x += 0x7fffu + ((x >> 16) & 1u);          // round-to-nearest-even
    return (unsigned short)(x >> 16);
}
__device__ __forceinline__ float4 ld4(const void* p, int idx4, bool isBf16) {
    if (isBf16) {
        ushort4 u = ((const ushort4*)p)[idx4];
        return make_float4(bf1(u.x), bf1(u.y), bf1(u.z), bf1(u.w));
    }
    return ((const float4*)p)[idx4];
}
__device__ __forceinline__ void st4bf(unsigned short* p, f32x4 v) {
    ushort4 u = { f2bf(v[0]), f2bf(v[1]), f2bf(v[2]), f2bf(v[3]) };
    *(ushort4*)p = u;
}
// Load one MFMA B-fragment (8 bf16) from a weight matrix of either dtype.
__device__ __forceinline__ bf16x8 ldWfrag(const void* W, int off, bool isBf16) {
    if (isBf16) return *(const bf16x8*)((const unsigned short*)W + off);
    const float* p = (const float*)W + off;
    float4 a = *(const float4*)p;
    float4 b = *(const float4*)(p + 4);
    bf16x8 r;
    r[0] = (short)f2bf(a.x); r[1] = (short)f2bf(a.y);
    r[2] = (short)f2bf(a.z); r[3] = (short)f2bf(a.w);
    r[4] = (short)f2bf(b.x); r[5] = (short)f2bf(b.y);
    r[6] = (short)f2bf(b.z); r[7] = (short)f2bf(b.w);
    return r;
}

// One block per (b,v). 8 waves: wave w -> head h=w>>1, half s=w&1.
// Projection phases (B/C/E): wave owns the 16-wide f/g-column slice
//   [32h + 16s, 32h + 16s + 16).
// Scores/PV: wave owns the t-half [16s, 16s+16) of its head, making the
//   scores->PV handoff wave-local (no extra barrier; still only 3 barriers).
// exp+mask fused into the scores epilogue via a ballot-broadcast mask bitset.
// LDS unchanged (63488 B): 2 blocks/CU x 8 waves = 16 waves/CU (50% cap),
// double the previous 4-wave config's 25% cap.
__global__ __launch_bounds__(512, 4)
void lane_attn_kernel(const void* __restrict__ veh,    // [T,B,V,F]
                      const void* __restrict__ lanes,  // [B,V,L,LF]
                      const void* __restrict__ maskp,  // [TH,B,V,L] uint8 or int32 (probed)
                      const void* __restrict__ Wk, const void* __restrict__ Wv,
                      const void* __restrict__ Wq, const void* __restrict__ Wc,
                      float* __restrict__ outp)        // [T,B,V,F] fp32
{
    const int bv    = blockIdx.x;
    const int tid   = threadIdx.x;
    const int w     = tid >> 6;
    const int h     = w >> 1;      // head
    const int shalf = w & 1;       // half within head
    const int lane  = tid & 63;
    const int quad  = lane >> 4;
    const int lm    = lane & 15;
    const int fbase = h * 32;
    const int fs    = fbase + shalf * 16;   // wave's 16-col f-slice

    // LDS overlays (ushort units):
    //   sQ    @0     [32][136]  (written C, read scores)
    //   sO    @0     [32][136]  (written PV; row/col-disjoint vs live sQ reads)
    //   sLanes@4352  [64][80]   (A..B)
    //   sVehB @9472  [32][136]  (A..C)
    //   sS    @4352  [4][32][72](scores..PV, overlays sLanes+sVehB after barrier 2)
    __shared__ __align__(16) unsigned short sRegion[13824];
    __shared__ __align__(16) unsigned short sK [64 * 136];
    __shared__ __align__(16) unsigned short sVt[128 * 72];
    unsigned short* sQ     = sRegion;
    unsigned short* sO     = sRegion;
    unsigned short* sLanes = sRegion + 4352;
    unsigned short* sVehB  = sRegion + 9472;
    unsigned short* sS     = sRegion + 4352;

    // ---------- per-wave probes (wave-uniform, no LDS/barrier) ----------
    const unsigned short* vh16 = (const unsigned short*)veh;
    const int field = (vh16[2 * lane] >> 7) & 0xFF;
    const bool isBf16 = __popcll(__ballot(field >= 100 && field <= 130)) >= 32;
    const unsigned char* mbp = (const unsigned char*)maskp;
    const bool maskByte = (__ballot(mbp[4 * lane + 1] != 0) != 0ULL);

    // ---------- per-lane mask OR over TH (l = lane) -> wave-uniform bitmask ----------
    bool ok;
    {
        const int* mi = (const int*)maskp;
        int o = 0;
        #pragma unroll
        for (int th = 0; th < TH_; ++th) {
            const size_t e = (size_t)th * (B_ * V_ * L_) + (size_t)bv * L_ + lane;
            o |= maskByte ? (int)mbp[e] : mi[e];
        }
        ok = (o != 0);
    }
    const unsigned long long mok = __ballot(ok);   // bit l = mask for lane-row l

    // ---------- preload weight fragments for this wave's 16-col slice ----------
    bf16x8 wbK[2], wbV[2], wq[4];
    #pragma unroll
    for (int kt = 0; kt < 2; ++kt) {
        const int off = (fs + lm) * 64 + kt * 32 + quad * 8;
        wbK[kt] = ldWfrag(Wk, off, isBf16);
        wbV[kt] = ldWfrag(Wv, off, isBf16);
    }
    #pragma unroll
    for (int kt = 0; kt < 4; ++kt)
        wq[kt] = ldWfrag(Wq, (fs + lm) * 128 + kt * 32 + quad * 8, isBf16);

    // ---------- Phase A: stage lanes[64][80] + veh[32][136] as bf16 ----------
    for (int u = tid; u < 64 * 16; u += 512) {
        const int l = u >> 4, c4 = u & 15;
        float4 x = ld4(lanes, bv * (L_ * LF_ / 4) + u, isBf16);
        ushort4 y = { f2bf(x.x), f2bf(x.y), f2bf(x.z), f2bf(x.w) };
        *(ushort4*)&sLanes[l * 80 + c4 * 4] = y;
    }
    for (int u = tid; u < 32 * 32; u += 512) {
        const int t = u >> 5, c4 = u & 31;
        ushort4 y = {0, 0, 0, 0};
        if (t < T_) {
            float4 x = ld4(veh, (t * (B_ * V_) + bv) * (F_ / 4) + c4, isBf16);
            y.x = f2bf(x.x); y.y = f2bf(x.y); y.z = f2bf(x.z); y.w = f2bf(x.w);
        }
        *(ushort4*)&sVehB[t * 136 + c4 * 4] = y;
    }
    __syncthreads();   // barrier 1: staging visible to all waves

    // ---------- Phase B: K/V projection for cols [fs, fs+16) ----------
    {
        f32x4 accK[4], accV[4];
        #pragma unroll
        for (int mt = 0; mt < 4; ++mt) { accK[mt] = (f32x4)0.f; accV[mt] = (f32x4)0.f; }
        #pragma unroll
        for (int kt = 0; kt < 2; ++kt) {
            bf16x8 a[4];
            #pragma unroll
            for (int mt = 0; mt < 4; ++mt)
                a[mt] = *(const bf16x8*)&sLanes[(mt * 16 + lm) * 80 + kt * 32 + quad * 8];
            #pragma unroll
            for (int mt = 0; mt < 4; ++mt) {
                accK[mt] = MFMA(a[mt], wbK[kt], accK[mt]);
                accV[mt] = MFMA(a[mt], wbV[kt], accV[mt]);
            }
        }
        const int f = fs + lm;
        #pragma unroll
        for (int mt = 0; mt < 4; ++mt) {
            const int l0 = mt * 16 + quad * 4;
            #pragma unroll
            for (int r = 0; r < 4; ++r) sK[(l0 + r) * 136 + f] = f2bf(accK[mt][r]);
            st4bf(&sVt[f * 72 + l0], accV[mt]);
        }
    }

    // ---------- Phase C: Q projection for cols [fs, fs+16), pre-scaled ----------
    {
        f32x4 acc[2];
        acc[0] = (f32x4)0.f; acc[1] = (f32x4)0.f;
        #pragma unroll
        for (int kt = 0; kt < 4; ++kt) {
            bf16x8 a[2];
            #pragma unroll
            for (int mt = 0; mt < 2; ++mt)
                a[mt] = *(const bf16x8*)&sVehB[(mt * 16 + lm) * 136 + kt * 32 + quad * 8];
            #pragma unroll
            for (int mt = 0; mt < 2; ++mt) acc[mt] = MFMA(a[mt], wq[kt], acc[mt]);
        }
        const float sc = 0.17677669529663687f;   // 1/sqrt(32)
        const int g = fs + lm;
        #pragma unroll
        for (int mt = 0; mt < 2; ++mt) {
            const int t0 = mt * 16 + quad * 4;
            #pragma unroll
            for (int r = 0; r < 4; ++r) sQ[(t0 + r) * 136 + g] = f2bf(acc[mt][r] * sc);
        }
    }

    // preload E fragments now (consumed after barrier 3; latency hidden)
    bf16x8 wc[4];
    #pragma unroll
    for (int kt = 0; kt < 4; ++kt)
        wc[kt] = ldWfrag(Wc, (fs + lm) * 128 + kt * 32 + quad * 8, isBf16);

    __syncthreads();   // barrier 2: sK/sQ/sVt visible; sLanes/sVehB dead -> sS overlay ok

    // ---------- Scores + fused exp/mask: wave owns t in [16s, 16s+16), all l ----------
    // S^T tile: A = K rows l (4 tiles), B = Q cols t (own 16). Output rows this wave
    // writes to sS are exactly the rows its own PV reads -> wave-local, no barrier.
    {
        bf16x8 a[4], b;
        #pragma unroll
        for (int mt = 0; mt < 4; ++mt)
            a[mt] = *(const bf16x8*)&sK[(mt * 16 + lm) * 136 + fbase + quad * 8];
        b = *(const bf16x8*)&sQ[(shalf * 16 + lm) * 136 + fbase + quad * 8];
        const int t = shalf * 16 + lm;
        const bool tok = (t < T_);
        #pragma unroll
        for (int mt = 0; mt < 4; ++mt) {
            f32x4 acc = MFMA(a[mt], b, (f32x4)0.f);
            const int l0 = mt * 16 + quad * 4;
            ushort4 y;
            y.x = f2bf((tok && ((mok >> (l0 + 0)) & 1)) ? __expf(acc[0]) : 0.f);
            y.y = f2bf((tok && ((mok >> (l0 + 1)) & 1)) ? __expf(acc[1]) : 0.f);
            y.z = f2bf((tok && ((mok >> (l0 + 2)) & 1)) ? __expf(acc[2]) : 0.f);
            y.w = f2bf((tok && ((mok >> (l0 + 3)) & 1)) ? __expf(acc[3]) : 0.f);
            *(ushort4*)&sS[(h * 32 + t) * 72 + l0] = y;
        }
    }

    // ---------- PV + ones-MFMA row sums; wave owns t in [16s,16s+16), all head cols ----------
    {
        bf16x8 bones;
        #pragma unroll
        for (int j = 0; j < 8; ++j) bones[j] = (short)0x3F80;   // 1.0bf
        f32x4 acc[2], ssum;
        acc[0] = (f32x4)0.f; acc[1] = (f32x4)0.f; ssum = (f32x4)0.f;
        #pragma unroll
        for (int kt = 0; kt < 2; ++kt) {
            bf16x8 a = *(const bf16x8*)&sS[(h * 32 + shalf * 16 + lm) * 72 + kt * 32 + quad * 8];
            bf16x8 b[2];
            #pragma unroll
            for (int nt = 0; nt < 2; ++nt)
                b[nt] = *(const bf16x8*)&sVt[(fbase + nt * 16 + lm) * 72 + kt * 32 + quad * 8];
            ssum = MFMA(a, bones, ssum);
            #pragma unroll
            for (int nt = 0; nt < 2; ++nt) acc[nt] = MFMA(a, b[nt], acc[nt]);
        }
        #pragma unroll
        for (int r = 0; r < 4; ++r) {
            const float sv = ssum[r];
            const float inv = (sv > 0.f) ? 1.f / sv : 0.f;   // pad/masked rows -> exact 0
            const int t = shalf * 16 + quad * 4 + r;
            #pragma unroll
            for (int nt = 0; nt < 2; ++nt)
                sO[t * 136 + fbase + nt * 16 + lm] = f2bf(acc[nt][r] * inv);
        }
    }

    // ---------- residual preload (exact fp32 path; issued before barrier 3) ----------
    float res[2][4];
    {
        const int g = fs + lm;
        #pragma unroll
        for (int mt = 0; mt < 2; ++mt)
            #pragma unroll
            for (int r = 0; r < 4; ++r) {
                const int t = mt * 16 + quad * 4 + r;
                float v = 0.f;
                if (t < T_) {
                    const size_t off = ((size_t)t * (B_ * V_) + bv) * F_ + g;
                    v = isBf16 ? bf1(((const unsigned short*)veh)[off])
                               : ((const float*)veh)[off];
                }
                res[mt][r] = v;
            }
    }
    __syncthreads();   // barrier 3: sO complete across waves

    // ---------- Phase E: out = O @ Wc^T + veh, cols [fs, fs+16) ----------
    {
        f32x4 acc[2];
        acc[0] = (f32x4)0.f; acc[1] = (f32x4)0.f;
        #pragma unroll
        for (int kt = 0; kt < 4; ++kt) {
            bf16x8 a[2];
            #pragma unroll
            for (int mt = 0; mt < 2; ++mt)
                a[mt] = *(const bf16x8*)&sO[(mt * 16 + lm) * 136 + kt * 32 + quad * 8];
            #pragma unroll
            for (int mt = 0; mt < 2; ++mt) acc[mt] = MFMA(a[mt], wc[kt], acc[mt]);
        }
        const int g = fs + lm;
        #pragma unroll
        for (int mt = 0; mt < 2; ++mt)
            #pragma unroll
            for (int r = 0; r < 4; ++r) {
                const int t = mt * 16 + quad * 4 + r;
                if (t < T_) {
                    const size_t off = ((size_t)t * (B_ * V_) + bv) * F_ + g;
                    outp[off] = acc[mt][r] + res[mt][r];
                }
            }
    }
}

extern "C" void kernel_launch(void* const* d_in, const int* in_sizes, int n_in,
                              void* d_out, int out_size, void* d_ws, size_t ws_size,
                              hipStream_t stream) {
    (void)in_sizes; (void)n_in; (void)out_size; (void)d_ws; (void)ws_size;
    lane_attn_kernel<<<dim3(B_ * V_), dim3(512), 0, stream>>>(
        d_in[0], d_in[1], d_in[2], d_in[3], d_in[4], d_in[5], d_in[6],
        (float*)d_out);
}